// Round 1
// baseline (746.596 us; speedup 1.0000x reference)
//
#include <hip/hip_runtime.h>

typedef __bf16 bf16x8 __attribute__((ext_vector_type(8)));
typedef float f32x4 __attribute__((ext_vector_type(4)));
typedef unsigned int uint32x4 __attribute__((ext_vector_type(4)));

#define DD 256
#define VV 1024
#define BN 16

__device__ __forceinline__ unsigned short f2bf(float f) {
    unsigned int b = __float_as_uint(f);
    b += 0x7FFFu + ((b >> 16) & 1u);
    return (unsigned short)(b >> 16);
}

// Prep: codebook f32 -> bf16 (row-major + transposed) + c2[v] = ||c_v||^2
__global__ __launch_bounds__(256) void vq_prep_kernel(
    const float* __restrict__ cb,
    unsigned short* __restrict__ cb_bf,   // [V][D]
    unsigned short* __restrict__ cbT_bf,  // [D][V]
    float* __restrict__ c2)               // [V]
{
    int v = blockIdx.x;
    int t = threadIdx.x;
    float val = cb[(size_t)v * DD + t];
    unsigned short h = f2bf(val);
    cb_bf[(size_t)v * DD + t] = h;
    cbT_bf[(size_t)t * VV + v] = h;
    float p = val * val;
#pragma unroll
    for (int d = 1; d < 64; d <<= 1) p += __shfl_xor(p, d);
    __shared__ float ps[4];
    if ((t & 63) == 0) ps[t >> 6] = p;
    __syncthreads();
    if (t == 0) c2[v] = ps[0] + ps[1] + ps[2] + ps[3];
}

// Main fused kernel: one block = BN(16) rows. 4 waves, each owns a V-chunk of 256.
// GEMM1 (scores) -> fused gumbel-softmax -> GEMM2 (prob @ codebook), all in one pass.
__global__ __launch_bounds__(256, 2) void vq_main_kernel(
    const float* __restrict__ x,          // [N][D]
    const float* __restrict__ gum,        // [N][V]
    const unsigned short* __restrict__ cb_bf,   // [V][D]
    const unsigned short* __restrict__ cbT_bf,  // [D][V]
    const float* __restrict__ c2g,        // [V]
    float* __restrict__ out_q,            // [N][D]
    float* __restrict__ out_p)            // [N][V]
{
    __shared__ unsigned short sx[BN][DD];   // 8 KB  x tile, bf16
    __shared__ unsigned short sp[BN][VV];   // 32 KB prob tile, bf16
    __shared__ float sq[BN][DD];            // 16 KB quantized partial reduce
    __shared__ float sc2[VV];               // 4 KB
    __shared__ float sx2[BN];
    __shared__ float sredA[4][BN];
    __shared__ float sredB[4][BN];

    const int tid  = threadIdx.x;
    const int wave = tid >> 6;
    const int lane = tid & 63;
    const int lrow = lane >> 4;   // 0..3
    const int lcol = lane & 15;   // 0..15
    const int row0 = blockIdx.x * BN;
    const int vb   = wave * 256;  // this wave's V-chunk base

    // ---- Phase 0: stage c2, x tile (f32 -> bf16) + x2 ----
    for (int i = tid; i < VV; i += 256) sc2[i] = c2g[i];
    {
        const int r  = (wave << 2) | lrow;   // 0..15
        const int d0 = lcol << 4;            // 16 floats per lane
        const float4* xp4 = reinterpret_cast<const float4*>(
            x + (size_t)(row0 + r) * DD + d0);
        float vals[16];
#pragma unroll
        for (int j = 0; j < 4; ++j) {
            float4 a = xp4[j];
            vals[4 * j + 0] = a.x; vals[4 * j + 1] = a.y;
            vals[4 * j + 2] = a.z; vals[4 * j + 3] = a.w;
        }
        float acc2 = 0.f;
#pragma unroll
        for (int j = 0; j < 16; ++j) {
            acc2 += vals[j] * vals[j];
            sx[r][d0 + j] = f2bf(vals[j]);
        }
#pragma unroll
        for (int d = 1; d < 16; d <<= 1) acc2 += __shfl_xor(acc2, d);
        if (lcol == 0) sx2[r] = acc2;
    }
    __syncthreads();

    // ---- GEMM1: S[16 rows][vb..vb+255] = x . cb^T  (M=16,N=16/tile,K=256) ----
    // A-frag: A[m = lane&15][k = (lane>>4)*8 + j]  (8 contiguous bf16 = 16B)
    bf16x8 afr[8];
#pragma unroll
    for (int kt = 0; kt < 8; ++kt)
        afr[kt] = __builtin_bit_cast(bf16x8,
            *reinterpret_cast<const uint32x4*>(&sx[lcol][kt * 32 + lrow * 8]));

    f32x4 acc[16];
#pragma unroll
    for (int nt = 0; nt < 16; ++nt) acc[nt] = (f32x4){0.f, 0.f, 0.f, 0.f};

#pragma unroll
    for (int nt = 0; nt < 16; ++nt) {
        const unsigned short* bp =
            cb_bf + (size_t)(vb + nt * 16 + lcol) * DD + lrow * 8;
#pragma unroll
        for (int kt = 0; kt < 8; ++kt) {
            bf16x8 bfr = __builtin_bit_cast(bf16x8,
                *reinterpret_cast<const uint32x4*>(bp + kt * 32));
            acc[nt] = __builtin_amdgcn_mfma_f32_16x16x32_bf16(afr[kt], bfr, acc[nt], 0, 0, 0);
        }
    }

    // ---- Softmax (fused gumbel): C-frag layout col = lane&15, row = (lane>>4)*4+reg ----
    float x2r[4], mp[4];
#pragma unroll
    for (int r = 0; r < 4; ++r) { x2r[r] = sx2[lrow * 4 + r]; mp[r] = -1e30f; }

#pragma unroll
    for (int nt = 0; nt < 16; ++nt) {
        const int v = vb + nt * 16 + lcol;
        const float c2v = sc2[v];
#pragma unroll
        for (int r = 0; r < 4; ++r) {
            const int row = lrow * 4 + r;
            float u = gum[(size_t)(row0 + row) * VV + v];
            u = fminf(fmaxf(u, 1e-10f), 1.0f - 1e-10f);
            float w = -logf(u);          // accurate near u ~ 1 (libm)
            float g = -__logf(w);        // outer log: abs err harmless
            float d2 = x2r[r] + c2v - 2.0f * acc[nt][r];
            d2 = fmaxf(d2, 1e-12f);
            float lg = (g - sqrtf(d2)) * 0.5f;   // (-dist + g) / TEMP, TEMP = 2
            acc[nt][r] = lg;
            mp[r] = fmaxf(mp[r], lg);
        }
    }
    // row max: reduce over 16 lanes (butterfly), then cross-wave via LDS
#pragma unroll
    for (int r = 0; r < 4; ++r) {
#pragma unroll
        for (int d = 1; d < 16; d <<= 1) mp[r] = fmaxf(mp[r], __shfl_xor(mp[r], d));
    }
    if (lcol == 0) {
#pragma unroll
        for (int r = 0; r < 4; ++r) sredA[wave][lrow * 4 + r] = mp[r];
    }
    __syncthreads();

    float mfin[4], ssum[4];
#pragma unroll
    for (int r = 0; r < 4; ++r) {
        const int row = lrow * 4 + r;
        mfin[r] = fmaxf(fmaxf(sredA[0][row], sredA[1][row]),
                        fmaxf(sredA[2][row], sredA[3][row]));
        ssum[r] = 0.f;
    }
#pragma unroll
    for (int nt = 0; nt < 16; ++nt) {
#pragma unroll
        for (int r = 0; r < 4; ++r) {
            float e = __expf(acc[nt][r] - mfin[r]);
            acc[nt][r] = e;
            ssum[r] += e;
        }
    }
#pragma unroll
    for (int r = 0; r < 4; ++r) {
#pragma unroll
        for (int d = 1; d < 16; d <<= 1) ssum[r] += __shfl_xor(ssum[r], d);
    }
    if (lcol == 0) {
#pragma unroll
        for (int r = 0; r < 4; ++r) sredB[wave][lrow * 4 + r] = ssum[r];
    }
    __syncthreads();

    float rinv[4];
#pragma unroll
    for (int r = 0; r < 4; ++r) {
        const int row = lrow * 4 + r;
        rinv[r] = 1.0f / (sredB[0][row] + sredB[1][row] + sredB[2][row] + sredB[3][row]);
    }

    // ---- prob: write f32 to global + bf16 to LDS ----
#pragma unroll
    for (int nt = 0; nt < 16; ++nt) {
        const int v = vb + nt * 16 + lcol;
#pragma unroll
        for (int r = 0; r < 4; ++r) {
            const int row = lrow * 4 + r;
            float p = acc[nt][r] * rinv[r];
            out_p[(size_t)(row0 + row) * VV + v] = p;
            sp[row][v] = f2bf(p);
        }
    }
    __syncthreads();

    // ---- GEMM2: quantized[16][256] = prob[16][1024] @ cb[1024][256] ----
    // Each wave does its own K-chunk (its v-chunk), partials reduced in LDS.
    bf16x8 pfr[8];
#pragma unroll
    for (int kt = 0; kt < 8; ++kt)
        pfr[kt] = __builtin_bit_cast(bf16x8,
            *reinterpret_cast<const uint32x4*>(&sp[lcol][vb + kt * 32 + lrow * 8]));

    f32x4 qacc[16];
#pragma unroll
    for (int nt = 0; nt < 16; ++nt) qacc[nt] = (f32x4){0.f, 0.f, 0.f, 0.f};

#pragma unroll
    for (int nt = 0; nt < 16; ++nt) {
        const unsigned short* bp =
            cbT_bf + (size_t)(nt * 16 + lcol) * VV + vb + lrow * 8;
#pragma unroll
        for (int kt = 0; kt < 8; ++kt) {
            bf16x8 bfr = __builtin_bit_cast(bf16x8,
                *reinterpret_cast<const uint32x4*>(bp + kt * 32));
            qacc[nt] = __builtin_amdgcn_mfma_f32_16x16x32_bf16(pfr[kt], bfr, qacc[nt], 0, 0, 0);
        }
    }

    // cross-wave reduce in LDS (sequential, barrier-separated)
    if (wave == 0) {
#pragma unroll
        for (int nt = 0; nt < 16; ++nt)
#pragma unroll
            for (int r = 0; r < 4; ++r)
                sq[lrow * 4 + r][nt * 16 + lcol] = qacc[nt][r];
    }
    __syncthreads();
    if (wave == 1) {
#pragma unroll
        for (int nt = 0; nt < 16; ++nt)
#pragma unroll
            for (int r = 0; r < 4; ++r)
                sq[lrow * 4 + r][nt * 16 + lcol] += qacc[nt][r];
    }
    __syncthreads();
    if (wave == 2) {
#pragma unroll
        for (int nt = 0; nt < 16; ++nt)
#pragma unroll
            for (int r = 0; r < 4; ++r)
                sq[lrow * 4 + r][nt * 16 + lcol] += qacc[nt][r];
    }
    __syncthreads();
    if (wave == 3) {
#pragma unroll
        for (int nt = 0; nt < 16; ++nt)
#pragma unroll
            for (int r = 0; r < 4; ++r)
                sq[lrow * 4 + r][nt * 16 + lcol] += qacc[nt][r];
    }
    __syncthreads();

    // write quantized (coalesced float4)
    {
        const int r  = (wave << 2) | lrow;
        const int d0 = lcol << 4;
        const float4* s4 = reinterpret_cast<const float4*>(&sq[r][d0]);
        float4* qp4 = reinterpret_cast<float4*>(out_q + (size_t)(row0 + r) * DD + d0);
#pragma unroll
        for (int j = 0; j < 4; ++j) qp4[j] = s4[j];
    }
}

extern "C" void kernel_launch(void* const* d_in, const int* in_sizes, int n_in,
                              void* d_out, int out_size, void* d_ws, size_t ws_size,
                              hipStream_t stream) {
    (void)in_sizes; (void)n_in; (void)out_size; (void)ws_size;
    const float* x   = (const float*)d_in[0];   // [16,4096,256]
    const float* cb  = (const float*)d_in[1];   // [1024,256]
    const float* gum = (const float*)d_in[2];   // [65536,1024]

    const int N = 16 * 4096;
    float* out_q = (float*)d_out;                       // [N][256]
    float* out_p = out_q + (size_t)N * DD;              // [N][1024]

    unsigned short* cb_bf  = (unsigned short*)d_ws;     // 512 KB
    unsigned short* cbT_bf = cb_bf + (size_t)VV * DD;   // 512 KB
    float* c2 = (float*)(cbT_bf + (size_t)DD * VV);     // 4 KB

    vq_prep_kernel<<<VV, 256, 0, stream>>>(cb, cb_bf, cbT_bf, c2);
    vq_main_kernel<<<N / BN, 256, 0, stream>>>(x, gum, cb_bf, cbT_bf, c2, out_q, out_p);
}

// Round 2
// 573.468 us; speedup vs baseline: 1.3019x; 1.3019x over previous
//
#include <hip/hip_runtime.h>

typedef __bf16 bf16x8 __attribute__((ext_vector_type(8)));
typedef float f32x4 __attribute__((ext_vector_type(4)));
typedef unsigned int uint32x4 __attribute__((ext_vector_type(4)));

#define DD 256
#define VV 1024
#define BN 16
#define SGS 1032   // padded row stride (elements) for g / prob union buffer
#define SXS 264    // padded row stride (elements) for x tile

__device__ __forceinline__ unsigned short f2bf(float f) {
    unsigned int b = __float_as_uint(f);
    b += 0x7FFFu + ((b >> 16) & 1u);
    return (unsigned short)(b >> 16);
}

// Prep: codebook f32 -> bf16 (row-major + transposed) + c2[v] = ||c_v||^2
__global__ __launch_bounds__(256) void vq_prep_kernel(
    const float* __restrict__ cb,
    unsigned short* __restrict__ cb_bf,   // [V][D]
    unsigned short* __restrict__ cbT_bf,  // [D][V]
    float* __restrict__ c2)               // [V]
{
    int v = blockIdx.x;
    int t = threadIdx.x;
    float val = cb[(size_t)v * DD + t];
    unsigned short h = f2bf(val);
    cb_bf[(size_t)v * DD + t] = h;
    cbT_bf[(size_t)t * VV + v] = h;
    float p = val * val;
#pragma unroll
    for (int d = 1; d < 64; d <<= 1) p += __shfl_xor(p, d);
    __shared__ float ps[4];
    if ((t & 63) == 0) ps[t >> 6] = p;
    __syncthreads();
    if (t == 0) c2[v] = ps[0] + ps[1] + ps[2] + ps[3];
}

// accurate-enough -log(u): log1p poly near 1 (relative accuracy where it matters),
// hardware log elsewhere.
__device__ __forceinline__ float neg_log_u(float u) {
    float t = u - 1.0f;  // exact for u in [0.5, 1]
    float p = t * (1.0f + t * (-0.5f + t * (0.33333333f + t * (-0.25f + t * 0.2f))));
    float lg = (u >= 0.984375f) ? p : __logf(u);
    return -lg;
}

// Main fused kernel: one block = BN(16) rows, 4 waves.
// GEMM1 waves own V-chunks of 256; GEMM2 waves own D-chunks of 64.
__global__ __launch_bounds__(256, 3) void vq_main_kernel(
    const float* __restrict__ x,          // [N][D]
    const float* __restrict__ gum,        // [N][V]
    const unsigned short* __restrict__ cb_bf,   // [V][D]
    const unsigned short* __restrict__ cbT_bf,  // [D][V]
    const float* __restrict__ c2g,        // [V]
    float* __restrict__ out_q,            // [N][D]
    float* __restrict__ out_p)            // [N][V]
{
    // union buffer: f16 gumbel-g tile [BN][SGS] first, later bf16 prob tile [BN][SGS]
    __shared__ __align__(16) unsigned short ubuf[BN * SGS];  // 33 KB
    __shared__ __align__(16) unsigned short sx[BN][SXS];     // 8.4 KB x tile, bf16
    __shared__ float sx2[BN];
    __shared__ float sredA[4][BN];
    __shared__ float sredB[4][BN];

    const int tid  = threadIdx.x;
    const int wave = tid >> 6;
    const int lane = tid & 63;
    const int lrow = lane >> 4;   // 0..3
    const int lcol = lane & 15;   // 0..15
    const int row0 = blockIdx.x * BN;
    const int vb   = wave * 256;  // GEMM1: this wave's V-chunk base
    const int dbw  = wave * 64;   // GEMM2: this wave's D-chunk base

    // ---- Phase 0: gumbel prefetch -> g (f16) in LDS; x tile; c2 regs ----
    // gumbel: row i, cols tid*4..+3, coalesced float4 stream
#pragma unroll
    for (int i = 0; i < BN; ++i) {
        const int col = tid << 2;
        float4 u4 = *reinterpret_cast<const float4*>(
            gum + (size_t)(row0 + i) * VV + col);
        float uu[4] = {u4.x, u4.y, u4.z, u4.w};
        ushort4 h;
        unsigned short* hp = reinterpret_cast<unsigned short*>(&h);
#pragma unroll
        for (int j = 0; j < 4; ++j) {
            float u = fminf(fmaxf(uu[j], 1e-10f), 1.0f - 1e-10f);
            float w = neg_log_u(u);       // -log(u) > 0
            float g = -__logf(w);         // gumbel
            _Float16 gh = (_Float16)g;
            hp[j] = __builtin_bit_cast(unsigned short, gh);
        }
        *reinterpret_cast<ushort4*>(&ubuf[i * SGS + col]) = h;
    }
    // x tile: row r, 16 floats per lane
    {
        const int r  = (wave << 2) | lrow;   // 0..15
        const int d0 = lcol << 4;
        const float4* xp4 = reinterpret_cast<const float4*>(
            x + (size_t)(row0 + r) * DD + d0);
        float vals[16];
#pragma unroll
        for (int j = 0; j < 4; ++j) {
            float4 a = xp4[j];
            vals[4 * j + 0] = a.x; vals[4 * j + 1] = a.y;
            vals[4 * j + 2] = a.z; vals[4 * j + 3] = a.w;
        }
        float acc2 = 0.f;
#pragma unroll
        for (int j = 0; j < 16; ++j) {
            acc2 += vals[j] * vals[j];
            sx[r][d0 + j] = f2bf(vals[j]);
        }
#pragma unroll
        for (int d = 1; d < 16; d <<= 1) acc2 += __shfl_xor(acc2, d);
        if (lcol == 0) sx2[r] = acc2;
    }
    // c2 for this wave's V-chunk, in registers
    float c2r[16];
#pragma unroll
    for (int nt = 0; nt < 16; ++nt) c2r[nt] = c2g[vb + nt * 16 + lcol];
    __syncthreads();

    // ---- GEMM1: S[16][vb..vb+255] = x . cb^T ----
    bf16x8 afr[8];
#pragma unroll
    for (int kt = 0; kt < 8; ++kt)
        afr[kt] = __builtin_bit_cast(bf16x8,
            *reinterpret_cast<const uint32x4*>(&sx[lcol][kt * 32 + lrow * 8]));

    f32x4 acc[16];
#pragma unroll
    for (int nt = 0; nt < 16; ++nt) acc[nt] = (f32x4){0.f, 0.f, 0.f, 0.f};

#pragma unroll
    for (int nt = 0; nt < 16; ++nt) {
        const unsigned short* bp =
            cb_bf + (size_t)(vb + nt * 16 + lcol) * DD + lrow * 8;
#pragma unroll
        for (int kt = 0; kt < 8; ++kt) {
            bf16x8 bfr = __builtin_bit_cast(bf16x8,
                *reinterpret_cast<const uint32x4*>(bp + kt * 32));
            acc[nt] = __builtin_amdgcn_mfma_f32_16x16x32_bf16(afr[kt], bfr, acc[nt], 0, 0, 0);
        }
    }

    // ---- logits: (-dist + g)/2 ; C-frag: col=lane&15, row=(lane>>4)*4+reg ----
    float x2r[4], mp[4];
#pragma unroll
    for (int r = 0; r < 4; ++r) { x2r[r] = sx2[lrow * 4 + r]; mp[r] = -1e30f; }

#pragma unroll
    for (int nt = 0; nt < 16; ++nt) {
        const int v = vb + nt * 16 + lcol;
        const float c2v = c2r[nt];
#pragma unroll
        for (int r = 0; r < 4; ++r) {
            const int row = lrow * 4 + r;
            _Float16 gh = __builtin_bit_cast(_Float16, ubuf[row * SGS + v]);
            float g = (float)gh;
            float d2 = x2r[r] + c2v - 2.0f * acc[nt][r];
            d2 = fmaxf(d2, 1e-12f);
            float lg = (g - sqrtf(d2)) * 0.5f;   // TEMP = 2
            acc[nt][r] = lg;
            mp[r] = fmaxf(mp[r], lg);
        }
    }
#pragma unroll
    for (int r = 0; r < 4; ++r) {
#pragma unroll
        for (int d = 1; d < 16; d <<= 1) mp[r] = fmaxf(mp[r], __shfl_xor(mp[r], d));
    }
    if (lcol == 0) {
#pragma unroll
        for (int r = 0; r < 4; ++r) sredA[wave][lrow * 4 + r] = mp[r];
    }
    __syncthreads();

    float mfin[4], ssum[4];
#pragma unroll
    for (int r = 0; r < 4; ++r) {
        const int row = lrow * 4 + r;
        mfin[r] = fmaxf(fmaxf(sredA[0][row], sredA[1][row]),
                        fmaxf(sredA[2][row], sredA[3][row]));
        ssum[r] = 0.f;
    }
#pragma unroll
    for (int nt = 0; nt < 16; ++nt) {
#pragma unroll
        for (int r = 0; r < 4; ++r) {
            float e = __expf(acc[nt][r] - mfin[r]);
            acc[nt][r] = e;
            ssum[r] += e;
        }
    }
#pragma unroll
    for (int r = 0; r < 4; ++r) {
#pragma unroll
        for (int d = 1; d < 16; d <<= 1) ssum[r] += __shfl_xor(ssum[r], d);
    }
    if (lcol == 0) {
#pragma unroll
        for (int r = 0; r < 4; ++r) sredB[wave][lrow * 4 + r] = ssum[r];
    }
    __syncthreads();   // also: all reads of g from ubuf are done -> reuse as prob

    float rinv[4];
#pragma unroll
    for (int r = 0; r < 4; ++r) {
        const int row = lrow * 4 + r;
        rinv[r] = 1.0f / (sredB[0][row] + sredB[1][row] + sredB[2][row] + sredB[3][row]);
    }

    // ---- prob: f32 to global + bf16 to LDS (ubuf reused) ----
#pragma unroll
    for (int nt = 0; nt < 16; ++nt) {
        const int v = vb + nt * 16 + lcol;
#pragma unroll
        for (int r = 0; r < 4; ++r) {
            const int row = lrow * 4 + r;
            float p = acc[nt][r] * rinv[r];
            out_p[(size_t)(row0 + row) * VV + v] = p;
            ubuf[row * SGS + v] = f2bf(p);
        }
    }
    __syncthreads();

    // ---- GEMM2: quantized[16][dbw..dbw+63] = prob[16][1024] @ cb[1024][256] ----
    f32x4 q[4];
#pragma unroll
    for (int nt = 0; nt < 4; ++nt) q[nt] = (f32x4){0.f, 0.f, 0.f, 0.f};

#pragma unroll
    for (int kt = 0; kt < 32; ++kt) {
        bf16x8 pfr = __builtin_bit_cast(bf16x8,
            *reinterpret_cast<const uint32x4*>(&ubuf[lcol * SGS + kt * 32 + lrow * 8]));
#pragma unroll
        for (int nt = 0; nt < 4; ++nt) {
            const unsigned short* bp =
                cbT_bf + (size_t)(dbw + nt * 16 + lcol) * VV + kt * 32 + lrow * 8;
            bf16x8 bfr = __builtin_bit_cast(bf16x8,
                *reinterpret_cast<const uint32x4*>(bp));
            q[nt] = __builtin_amdgcn_mfma_f32_16x16x32_bf16(pfr, bfr, q[nt], 0, 0, 0);
        }
    }

    // direct store (no cross-wave reduce needed: waves own disjoint D-chunks)
#pragma unroll
    for (int nt = 0; nt < 4; ++nt) {
        const int d = dbw + nt * 16 + lcol;
#pragma unroll
        for (int r = 0; r < 4; ++r) {
            const int row = lrow * 4 + r;
            out_q[(size_t)(row0 + row) * DD + d] = q[nt][r];
        }
    }
}

extern "C" void kernel_launch(void* const* d_in, const int* in_sizes, int n_in,
                              void* d_out, int out_size, void* d_ws, size_t ws_size,
                              hipStream_t stream) {
    (void)in_sizes; (void)n_in; (void)out_size; (void)ws_size;
    const float* x   = (const float*)d_in[0];   // [16,4096,256]
    const float* cb  = (const float*)d_in[1];   // [1024,256]
    const float* gum = (const float*)d_in[2];   // [65536,1024]

    const int N = 16 * 4096;
    float* out_q = (float*)d_out;                       // [N][256]
    float* out_p = out_q + (size_t)N * DD;              // [N][1024]

    unsigned short* cb_bf  = (unsigned short*)d_ws;     // 512 KB
    unsigned short* cbT_bf = cb_bf + (size_t)VV * DD;   // 512 KB
    float* c2 = (float*)(cbT_bf + (size_t)DD * VV);     // 4 KB

    vq_prep_kernel<<<VV, 256, 0, stream>>>(cb, cb_bf, cbT_bf, c2);
    vq_main_kernel<<<N / BN, 256, 0, stream>>>(x, gum, cb_bf, cbT_bf, c2, out_q, out_p);
}

// Round 3
// 570.105 us; speedup vs baseline: 1.3096x; 1.0059x over previous
//
#include <hip/hip_runtime.h>

typedef __bf16 bf16x8 __attribute__((ext_vector_type(8)));
typedef float f32x4 __attribute__((ext_vector_type(4)));
typedef unsigned int uint32x4 __attribute__((ext_vector_type(4)));

#define DD 256
#define VV 1024
#define BN 16

// XOR swizzle on ushort index: flips byte-bits 4..6 by row -> bank-spread for
// stride-2048B column reads (GEMM2 b128) while keeping 8B/16B alignment.
#define SWZ(row, col) ((((row) * VV) + (col)) ^ (((row) & 7) << 3))

__device__ __forceinline__ unsigned short f2bf(float f) {
    unsigned int b = __float_as_uint(f);
    b += 0x7FFFu + ((b >> 16) & 1u);
    return (unsigned short)(b >> 16);
}

// Prep: codebook f32 -> bf16 (row-major + transposed) + c2[v] = ||c_v||^2
__global__ __launch_bounds__(256) void vq_prep_kernel(
    const float* __restrict__ cb,
    unsigned short* __restrict__ cb_bf,   // [V][D]
    unsigned short* __restrict__ cbT_bf,  // [D][V]
    float* __restrict__ c2)               // [V]
{
    int v = blockIdx.x;
    int t = threadIdx.x;
    float val = cb[(size_t)v * DD + t];
    unsigned short h = f2bf(val);
    cb_bf[(size_t)v * DD + t] = h;
    cbT_bf[(size_t)t * VV + v] = h;
    float p = val * val;
#pragma unroll
    for (int d = 1; d < 64; d <<= 1) p += __shfl_xor(p, d);
    __shared__ float ps[4];
    if ((t & 63) == 0) ps[t >> 6] = p;
    __syncthreads();
    if (t == 0) c2[v] = ps[0] + ps[1] + ps[2] + ps[3];
}

// accurate-enough -log(u): log1p poly near 1 (relative accuracy where it matters),
// hardware log elsewhere.
__device__ __forceinline__ float neg_log_u(float u) {
    float t = u - 1.0f;  // exact for u in [0.5, 1]
    float p = t * (1.0f + t * (-0.5f + t * (0.33333333f + t * (-0.25f + t * 0.2f))));
    float lg = (u >= 0.984375f) ? p : __logf(u);
    return -lg;
}

// Main fused kernel: one block = BN(16) rows, 4 waves.
// GEMM1 waves own V-chunks of 256; GEMM2 waves own D-chunks of 64.
__global__ __launch_bounds__(256, 4) void vq_main_kernel(
    const float* __restrict__ x,          // [N][D]
    const float* __restrict__ gum,        // [N][V]
    const unsigned short* __restrict__ cb_bf,   // [V][D]
    const unsigned short* __restrict__ cbT_bf,  // [D][V]
    const float* __restrict__ c2g,        // [V]
    float* __restrict__ out_q,            // [N][D]
    float* __restrict__ out_p)            // [N][V]
{
    // union buffer: f16 gumbel-g tile first, later bf16 prob tile (both swizzled)
    __shared__ __align__(16) unsigned short ubuf[BN * VV];  // 32 KB
    __shared__ float sx2[BN];
    __shared__ float sredA[4][BN];
    __shared__ float sredB[4][BN];

    const int tid  = threadIdx.x;
    const int wave = tid >> 6;
    const int lane = tid & 63;
    const int lrow = lane >> 4;   // 0..3
    const int lcol = lane & 15;   // 0..15
    const int row0 = blockIdx.x * BN;
    const int vb   = wave * 256;  // GEMM1: this wave's V-chunk base
    const int dbw  = wave * 64;   // GEMM2: this wave's D-chunk base

    // ---- Phase 0a: gumbel prefetch -> g (f16) into swizzled LDS ----
#pragma unroll
    for (int i = 0; i < BN; ++i) {
        const int col = tid << 2;
        float4 u4 = *reinterpret_cast<const float4*>(
            gum + (size_t)(row0 + i) * VV + col);
        float uu[4] = {u4.x, u4.y, u4.z, u4.w};
        ushort4 h;
        unsigned short* hp = reinterpret_cast<unsigned short*>(&h);
#pragma unroll
        for (int j = 0; j < 4; ++j) {
            float u = fminf(fmaxf(uu[j], 1e-10f), 1.0f - 1e-10f);
            float w = neg_log_u(u);       // -log(u) > 0
            float g = -__logf(w);         // gumbel
            _Float16 gh = (_Float16)g;
            hp[j] = __builtin_bit_cast(unsigned short, gh);
        }
        *reinterpret_cast<ushort4*>(&ubuf[SWZ(i, col)]) = h;
    }

    // ---- Phase 0b: x -> A-fragments in registers + x2 via shuffles ----
    // A[m = lcol][k = kt*32 + lrow*8 + j]: 32B of row (row0+lcol) per kt.
    bf16x8 afr[8];
    float acc2 = 0.f;
    {
        const float* xrow = x + (size_t)(row0 + lcol) * DD + lrow * 8;
#pragma unroll
        for (int kt = 0; kt < 8; ++kt) {
            float4 a = *reinterpret_cast<const float4*>(xrow + kt * 32);
            float4 b = *reinterpret_cast<const float4*>(xrow + kt * 32 + 4);
            float v8[8] = {a.x, a.y, a.z, a.w, b.x, b.y, b.z, b.w};
            uint32x4 w;
#pragma unroll
            for (int j = 0; j < 4; ++j) {
                acc2 += v8[2 * j] * v8[2 * j] + v8[2 * j + 1] * v8[2 * j + 1];
                w[j] = (unsigned int)f2bf(v8[2 * j]) |
                       ((unsigned int)f2bf(v8[2 * j + 1]) << 16);
            }
            afr[kt] = __builtin_bit_cast(bf16x8, w);
        }
        acc2 += __shfl_xor(acc2, 16);
        acc2 += __shfl_xor(acc2, 32);   // x2[row = lcol], replicated
        if (wave == 0 && lane < 16) sx2[lane] = acc2;
    }

    // ---- GEMM1: S[16][vb..vb+255] = x . cb^T (no LDS dependency) ----
    f32x4 acc[16];
#pragma unroll
    for (int nt = 0; nt < 16; ++nt) acc[nt] = (f32x4){0.f, 0.f, 0.f, 0.f};

#pragma unroll
    for (int nt = 0; nt < 16; ++nt) {
        const unsigned short* bp =
            cb_bf + (size_t)(vb + nt * 16 + lcol) * DD + lrow * 8;
#pragma unroll
        for (int kt = 0; kt < 8; ++kt) {
            bf16x8 bfr = __builtin_bit_cast(bf16x8,
                *reinterpret_cast<const uint32x4*>(bp + kt * 32));
            acc[nt] = __builtin_amdgcn_mfma_f32_16x16x32_bf16(afr[kt], bfr, acc[nt], 0, 0, 0);
        }
    }

    // c2 for this wave's V-chunk (L2-hit loads; latency partly covered by barrier)
    float c2r[16];
#pragma unroll
    for (int nt = 0; nt < 16; ++nt) c2r[nt] = c2g[vb + nt * 16 + lcol];

    __syncthreads();   // g-tile + sx2 now visible

    // ---- logits: (-dist + g)/2 ; C-frag: col=lane&15, row=(lane>>4)*4+reg ----
    float x2r[4], mp[4];
#pragma unroll
    for (int r = 0; r < 4; ++r) { x2r[r] = sx2[lrow * 4 + r]; mp[r] = -1e30f; }

#pragma unroll
    for (int nt = 0; nt < 16; ++nt) {
        const int v = vb + nt * 16 + lcol;
        const float c2v = c2r[nt];
#pragma unroll
        for (int r = 0; r < 4; ++r) {
            const int row = lrow * 4 + r;
            _Float16 gh = __builtin_bit_cast(_Float16, ubuf[SWZ(row, v)]);
            float g = (float)gh;
            float d2 = x2r[r] + c2v - 2.0f * acc[nt][r];
            d2 = fmaxf(d2, 1e-12f);
            float lg = (g - sqrtf(d2)) * 0.5f;   // TEMP = 2
            acc[nt][r] = lg;
            mp[r] = fmaxf(mp[r], lg);
        }
    }
#pragma unroll
    for (int r = 0; r < 4; ++r) {
#pragma unroll
        for (int d = 1; d < 16; d <<= 1) mp[r] = fmaxf(mp[r], __shfl_xor(mp[r], d));
    }
    if (lcol == 0) {
#pragma unroll
        for (int r = 0; r < 4; ++r) sredA[wave][lrow * 4 + r] = mp[r];
    }
    __syncthreads();

    float mfin[4], ssum[4];
#pragma unroll
    for (int r = 0; r < 4; ++r) {
        const int row = lrow * 4 + r;
        mfin[r] = fmaxf(fmaxf(sredA[0][row], sredA[1][row]),
                        fmaxf(sredA[2][row], sredA[3][row]));
        ssum[r] = 0.f;
    }
#pragma unroll
    for (int nt = 0; nt < 16; ++nt) {
#pragma unroll
        for (int r = 0; r < 4; ++r) {
            float e = __expf(acc[nt][r] - mfin[r]);
            acc[nt][r] = e;
            ssum[r] += e;
        }
    }
#pragma unroll
    for (int r = 0; r < 4; ++r) {
#pragma unroll
        for (int d = 1; d < 16; d <<= 1) ssum[r] += __shfl_xor(ssum[r], d);
    }
    if (lcol == 0) {
#pragma unroll
        for (int r = 0; r < 4; ++r) sredB[wave][lrow * 4 + r] = ssum[r];
    }
    __syncthreads();   // all g reads done -> ubuf reusable as prob

    float rinv[4];
#pragma unroll
    for (int r = 0; r < 4; ++r) {
        const int row = lrow * 4 + r;
        rinv[r] = 1.0f / (sredB[0][row] + sredB[1][row] + sredB[2][row] + sredB[3][row]);
    }

    // ---- prob: f32 to global + bf16 to LDS (ubuf reused, swizzled) ----
#pragma unroll
    for (int nt = 0; nt < 16; ++nt) {
        const int v = vb + nt * 16 + lcol;
#pragma unroll
        for (int r = 0; r < 4; ++r) {
            const int row = lrow * 4 + r;
            float p = acc[nt][r] * rinv[r];
            out_p[(size_t)(row0 + row) * VV + v] = p;
            ubuf[SWZ(row, v)] = f2bf(p);
        }
    }
    __syncthreads();

    // ---- GEMM2: quantized[16][dbw..dbw+63] = prob[16][1024] @ cb[1024][256] ----
    f32x4 q[4];
#pragma unroll
    for (int nt = 0; nt < 4; ++nt) q[nt] = (f32x4){0.f, 0.f, 0.f, 0.f};

#pragma unroll
    for (int kt = 0; kt < 32; ++kt) {
        bf16x8 pfr = __builtin_bit_cast(bf16x8,
            *reinterpret_cast<const uint32x4*>(&ubuf[SWZ(lcol, kt * 32 + lrow * 8)]));
#pragma unroll
        for (int nt = 0; nt < 4; ++nt) {
            const unsigned short* bp =
                cbT_bf + (size_t)(dbw + nt * 16 + lcol) * VV + kt * 32 + lrow * 8;
            bf16x8 bfr = __builtin_bit_cast(bf16x8,
                *reinterpret_cast<const uint32x4*>(bp));
            q[nt] = __builtin_amdgcn_mfma_f32_16x16x32_bf16(pfr, bfr, q[nt], 0, 0, 0);
        }
    }

    // direct store (waves own disjoint D-chunks)
#pragma unroll
    for (int nt = 0; nt < 4; ++nt) {
        const int d = dbw + nt * 16 + lcol;
#pragma unroll
        for (int r = 0; r < 4; ++r) {
            const int row = lrow * 4 + r;
            out_q[(size_t)(row0 + row) * DD + d] = q[nt][r];
        }
    }
}

extern "C" void kernel_launch(void* const* d_in, const int* in_sizes, int n_in,
                              void* d_out, int out_size, void* d_ws, size_t ws_size,
                              hipStream_t stream) {
    (void)in_sizes; (void)n_in; (void)out_size; (void)ws_size;
    const float* x   = (const float*)d_in[0];   // [16,4096,256]
    const float* cb  = (const float*)d_in[1];   // [1024,256]
    const float* gum = (const float*)d_in[2];   // [65536,1024]

    const int N = 16 * 4096;
    float* out_q = (float*)d_out;                       // [N][256]
    float* out_p = out_q + (size_t)N * DD;              // [N][1024]

    unsigned short* cb_bf  = (unsigned short*)d_ws;     // 512 KB
    unsigned short* cbT_bf = cb_bf + (size_t)VV * DD;   // 512 KB
    float* c2 = (float*)(cbT_bf + (size_t)DD * VV);     // 4 KB

    vq_prep_kernel<<<VV, 256, 0, stream>>>(cb, cb_bf, cbT_bf, c2);
    vq_main_kernel<<<N / BN, 256, 0, stream>>>(x, gum, cb_bf, cbT_bf, c2, out_q, out_p);
}

// Round 4
// 565.263 us; speedup vs baseline: 1.3208x; 1.0086x over previous
//
#include <hip/hip_runtime.h>

typedef __bf16 bf16x8 __attribute__((ext_vector_type(8)));
typedef float f32x4 __attribute__((ext_vector_type(4)));
typedef unsigned int uint32x4 __attribute__((ext_vector_type(4)));

#define DD 256
#define VV 1024
#define BN 16

// XOR swizzle on ushort index: flips element-index bits 3..5 by row ->
// bank-spread for stride-2KB column reads while keeping 16B chunks intact.
#define SWZ(row, col) ((((row) * VV) + (col)) ^ (((row) & 7) << 3))

__device__ __forceinline__ unsigned short f2bf(float f) {
    unsigned int b = __float_as_uint(f);
    b += 0x7FFFu + ((b >> 16) & 1u);
    return (unsigned short)(b >> 16);
}

// Prep: codebook f32 -> bf16 (row-major + transposed) + c2[v] = ||c_v||^2
__global__ __launch_bounds__(256) void vq_prep_kernel(
    const float* __restrict__ cb,
    unsigned short* __restrict__ cb_bf,   // [V][D]
    unsigned short* __restrict__ cbT_bf,  // [D][V]
    float* __restrict__ c2)               // [V]
{
    int v = blockIdx.x;
    int t = threadIdx.x;
    float val = cb[(size_t)v * DD + t];
    unsigned short h = f2bf(val);
    cb_bf[(size_t)v * DD + t] = h;
    cbT_bf[(size_t)t * VV + v] = h;
    float p = val * val;
#pragma unroll
    for (int d = 1; d < 64; d <<= 1) p += __shfl_xor(p, d);
    __shared__ float ps[4];
    if ((t & 63) == 0) ps[t >> 6] = p;
    __syncthreads();
    if (t == 0) c2[v] = ps[0] + ps[1] + ps[2] + ps[3];
}

// accurate-enough -log(u): log1p poly near 1 (relative accuracy where it matters),
// hardware log elsewhere.
__device__ __forceinline__ float neg_log_u(float u) {
    float t = u - 1.0f;  // exact for u in [0.5, 1]
    float p = t * (1.0f + t * (-0.5f + t * (0.33333333f + t * (-0.25f + t * 0.2f))));
    float lg = (u >= 0.984375f) ? p : __logf(u);
    return -lg;
}

// Main fused kernel: one block = BN(16) rows, 4 waves.
// GEMM1 waves own V-chunks of 256; GEMM2 waves own D-chunks of 64.
__global__ __launch_bounds__(256, 3) void vq_main_kernel(
    const float* __restrict__ x,          // [N][D]
    const float* __restrict__ gum,        // [N][V]
    const unsigned short* __restrict__ cb_bf,   // [V][D]
    const unsigned short* __restrict__ cbT_bf,  // [D][V]
    const float* __restrict__ c2g,        // [V]
    float* __restrict__ out_q,            // [N][D]
    float* __restrict__ out_p)            // [N][V]
{
    // union buffer: f16 gumbel-g tile first, later bf16 prob tile (both swizzled)
    __shared__ __align__(16) unsigned short ubuf[BN * VV];  // 32 KB
    __shared__ float sx2[BN];
    __shared__ float sredA[4][BN];
    __shared__ float sredB[4][BN];

    const int tid  = threadIdx.x;
    const int wave = tid >> 6;
    const int lane = tid & 63;
    const int lrow = lane >> 4;   // 0..3
    const int lcol = lane & 15;   // 0..15
    const int row0 = blockIdx.x * BN;
    const int vb   = wave * 256;  // GEMM1: this wave's V-chunk base
    const int dbw  = wave * 64;   // GEMM2: this wave's D-chunk base

    // ---- Phase 0a: gumbel prefetch (all 16 loads in flight) -> g (f16) LDS ----
    {
        float4 u4[BN];
#pragma unroll
        for (int i = 0; i < BN; ++i)
            u4[i] = *reinterpret_cast<const float4*>(
                gum + (size_t)(row0 + i) * VV + (tid << 2));
#pragma unroll
        for (int i = 0; i < BN; ++i) {
            float uu[4] = {u4[i].x, u4[i].y, u4[i].z, u4[i].w};
            ushort4 h;
            unsigned short* hp = reinterpret_cast<unsigned short*>(&h);
#pragma unroll
            for (int j = 0; j < 4; ++j) {
                float u = fminf(fmaxf(uu[j], 1e-10f), 1.0f - 1e-10f);
                float w = neg_log_u(u);       // -log(u) > 0
                float g = -__logf(w);         // gumbel
                _Float16 gh = (_Float16)g;
                hp[j] = __builtin_bit_cast(unsigned short, gh);
            }
            *reinterpret_cast<ushort4*>(&ubuf[SWZ(i, tid << 2)]) = h;
        }
    }

    // ---- Phase 0b: x -> A-fragments in registers + x2 via shuffles ----
    bf16x8 afr[8];
    float acc2 = 0.f;
    {
        const float* xrow = x + (size_t)(row0 + lcol) * DD + lrow * 8;
        float4 xa[8], xb[8];
#pragma unroll
        for (int kt = 0; kt < 8; ++kt) {
            xa[kt] = *reinterpret_cast<const float4*>(xrow + kt * 32);
            xb[kt] = *reinterpret_cast<const float4*>(xrow + kt * 32 + 4);
        }
#pragma unroll
        for (int kt = 0; kt < 8; ++kt) {
            float v8[8] = {xa[kt].x, xa[kt].y, xa[kt].z, xa[kt].w,
                           xb[kt].x, xb[kt].y, xb[kt].z, xb[kt].w};
            uint32x4 w;
#pragma unroll
            for (int j = 0; j < 4; ++j) {
                acc2 += v8[2 * j] * v8[2 * j] + v8[2 * j + 1] * v8[2 * j + 1];
                w[j] = (unsigned int)f2bf(v8[2 * j]) |
                       ((unsigned int)f2bf(v8[2 * j + 1]) << 16);
            }
            afr[kt] = __builtin_bit_cast(bf16x8, w);
        }
        acc2 += __shfl_xor(acc2, 16);
        acc2 += __shfl_xor(acc2, 32);   // x2[row = lcol], replicated
        if (wave == 0 && lane < 16) sx2[lane] = acc2;
    }

    // ---- GEMM1: S[16][vb..vb+255] = x . cb^T (no LDS dependency) ----
    f32x4 acc[16];
#pragma unroll
    for (int nt = 0; nt < 16; ++nt) acc[nt] = (f32x4){0.f, 0.f, 0.f, 0.f};

#pragma unroll
    for (int nt = 0; nt < 16; ++nt) {
        const unsigned short* bp =
            cb_bf + (size_t)(vb + nt * 16 + lcol) * DD + lrow * 8;
#pragma unroll
        for (int kt = 0; kt < 8; ++kt) {
            bf16x8 bfr = __builtin_bit_cast(bf16x8,
                *reinterpret_cast<const uint32x4*>(bp + kt * 32));
            acc[nt] = __builtin_amdgcn_mfma_f32_16x16x32_bf16(afr[kt], bfr, acc[nt], 0, 0, 0);
        }
    }

    // c2 for this wave's V-chunk
    float c2r[16];
#pragma unroll
    for (int nt = 0; nt < 16; ++nt) c2r[nt] = c2g[vb + nt * 16 + lcol];

    __syncthreads();   // g-tile + sx2 now visible

    // ---- logits + ONE-PASS softmax (wave-local max, local sum of exp) ----
    // C-frag: col=lane&15, row=(lane>>4)*4+reg
    float x2r[4], mp[4];
#pragma unroll
    for (int r = 0; r < 4; ++r) { x2r[r] = sx2[lrow * 4 + r]; mp[r] = -1e30f; }

#pragma unroll
    for (int nt = 0; nt < 16; ++nt) {
        const int v = vb + nt * 16 + lcol;
        const float c2v = c2r[nt];
#pragma unroll
        for (int r = 0; r < 4; ++r) {
            const int row = lrow * 4 + r;
            _Float16 gh = __builtin_bit_cast(_Float16, ubuf[SWZ(row, v)]);
            float g = (float)gh;
            float d2 = x2r[r] + c2v - 2.0f * acc[nt][r];
            d2 = fmaxf(d2, 1e-12f);
            float lg = (g - sqrtf(d2)) * 0.5f;   // TEMP = 2
            acc[nt][r] = lg;
            mp[r] = fmaxf(mp[r], lg);
        }
    }
#pragma unroll
    for (int r = 0; r < 4; ++r) {
#pragma unroll
        for (int d = 1; d < 16; d <<= 1) mp[r] = fmaxf(mp[r], __shfl_xor(mp[r], d));
    }
    // exp vs wave-local max + local sum
    float ssum[4] = {0.f, 0.f, 0.f, 0.f};
#pragma unroll
    for (int nt = 0; nt < 16; ++nt) {
#pragma unroll
        for (int r = 0; r < 4; ++r) {
            float e = __expf(acc[nt][r] - mp[r]);
            acc[nt][r] = e;
            ssum[r] += e;
        }
    }
#pragma unroll
    for (int r = 0; r < 4; ++r) {
#pragma unroll
        for (int d = 1; d < 16; d <<= 1) ssum[r] += __shfl_xor(ssum[r], d);
    }
    if (lcol == 0) {
#pragma unroll
        for (int r = 0; r < 4; ++r) {
            sredA[wave][lrow * 4 + r] = mp[r];
            sredB[wave][lrow * 4 + r] = ssum[r];
        }
    }
    __syncthreads();

    // combine: global max + rescaled sum; f = exp(m_w - m) / Z
    float f[4];
#pragma unroll
    for (int r = 0; r < 4; ++r) {
        const int row = lrow * 4 + r;
        float m0 = sredA[0][row], m1 = sredA[1][row];
        float m2 = sredA[2][row], m3 = sredA[3][row];
        float m = fmaxf(fmaxf(m0, m1), fmaxf(m2, m3));
        float Z = sredB[0][row] * __expf(m0 - m) + sredB[1][row] * __expf(m1 - m) +
                  sredB[2][row] * __expf(m2 - m) + sredB[3][row] * __expf(m3 - m);
        f[r] = __expf(mp[r] - m) / Z;
    }

    // ---- prob -> bf16 LDS only (no global stores before the barrier) ----
#pragma unroll
    for (int nt = 0; nt < 16; ++nt) {
        const int v = vb + nt * 16 + lcol;
#pragma unroll
        for (int r = 0; r < 4; ++r) {
            const int row = lrow * 4 + r;
            ubuf[SWZ(row, v)] = f2bf(acc[nt][r] * f[r]);
        }
    }
    __syncthreads();

    // ---- GEMM2: quantized[16][dbw..dbw+63] = prob[16][1024] @ cb[1024][256] ----
    f32x4 q[4];
#pragma unroll
    for (int nt = 0; nt < 4; ++nt) q[nt] = (f32x4){0.f, 0.f, 0.f, 0.f};

#pragma unroll
    for (int kt = 0; kt < 32; ++kt) {
        bf16x8 pfr = __builtin_bit_cast(bf16x8,
            *reinterpret_cast<const uint32x4*>(&ubuf[SWZ(lcol, kt * 32 + lrow * 8)]));
#pragma unroll
        for (int nt = 0; nt < 4; ++nt) {
            const unsigned short* bp =
                cbT_bf + (size_t)(dbw + nt * 16 + lcol) * VV + kt * 32 + lrow * 8;
            bf16x8 bfr = __builtin_bit_cast(bf16x8,
                *reinterpret_cast<const uint32x4*>(bp));
            q[nt] = __builtin_amdgcn_mfma_f32_16x16x32_bf16(pfr, bfr, q[nt], 0, 0, 0);
        }
    }

    // ---- out_p: reconstruct f32 from LDS bf16, coalesced stores ----
    // (overlaps GEMM2 retirement; bf16 round-trip error ~4e-3 << threshold)
    {
        const int prow = (wave << 2) | lrow;   // 0..15
        float* oprow = out_p + (size_t)(row0 + prow) * VV;
#pragma unroll
        for (int c = 0; c < 8; ++c) {
            const int col = c * 128 + lcol * 8;
            uint32x4 pw = *reinterpret_cast<const uint32x4*>(&ubuf[SWZ(prow, col)]);
            float o[8];
#pragma unroll
            for (int j = 0; j < 4; ++j) {
                o[2 * j]     = __uint_as_float(pw[j] << 16);
                o[2 * j + 1] = __uint_as_float(pw[j] & 0xFFFF0000u);
            }
            *reinterpret_cast<float4*>(oprow + col)     = (float4){o[0], o[1], o[2], o[3]};
            *reinterpret_cast<float4*>(oprow + col + 4) = (float4){o[4], o[5], o[6], o[7]};
        }
    }

    // direct store (waves own disjoint D-chunks)
#pragma unroll
    for (int nt = 0; nt < 4; ++nt) {
        const int d = dbw + nt * 16 + lcol;
#pragma unroll
        for (int r = 0; r < 4; ++r) {
            const int row = lrow * 4 + r;
            out_q[(size_t)(row0 + row) * DD + d] = q[nt][r];
        }
    }
}

extern "C" void kernel_launch(void* const* d_in, const int* in_sizes, int n_in,
                              void* d_out, int out_size, void* d_ws, size_t ws_size,
                              hipStream_t stream) {
    (void)in_sizes; (void)n_in; (void)out_size; (void)ws_size;
    const float* x   = (const float*)d_in[0];   // [16,4096,256]
    const float* cb  = (const float*)d_in[1];   // [1024,256]
    const float* gum = (const float*)d_in[2];   // [65536,1024]

    const int N = 16 * 4096;
    float* out_q = (float*)d_out;                       // [N][256]
    float* out_p = out_q + (size_t)N * DD;              // [N][1024]

    unsigned short* cb_bf  = (unsigned short*)d_ws;     // 512 KB
    unsigned short* cbT_bf = cb_bf + (size_t)VV * DD;   // 512 KB
    float* c2 = (float*)(cbT_bf + (size_t)DD * VV);     // 4 KB

    vq_prep_kernel<<<VV, 256, 0, stream>>>(cb, cb_bf, cbT_bf, c2);
    vq_main_kernel<<<N / BN, 256, 0, stream>>>(x, gum, cb_bf, cbT_bf, c2, out_q, out_p);
}

// Round 5
// 513.753 us; speedup vs baseline: 1.4532x; 1.1003x over previous
//
#include <hip/hip_runtime.h>

typedef __bf16 bf16x8 __attribute__((ext_vector_type(8)));
typedef float f32x4 __attribute__((ext_vector_type(4)));
typedef unsigned int uint32x4 __attribute__((ext_vector_type(4)));

#define DD 256
#define VV 1024
#define BN 16
#define KE 288   // extended K: 256 dot + {-c2/2 hi, -c2/2 lo, 0 x 30}

// XOR swizzle on ushort index: flips element-index bits 3..5 by row ->
// bank-spread for stride-2KB column reads while keeping 8B/16B chunks intact.
#define SWZ(row, col) ((((row) * VV) + (col)) ^ (((row) & 7) << 3))

__device__ __forceinline__ unsigned short f2bf(float f) {
    unsigned int b = __float_as_uint(f);
    b += 0x7FFFu + ((b >> 16) & 1u);
    return (unsigned short)(b >> 16);
}

// Prep: cb_ext[v][288] = [bf16 codebook row | -c2/2 hi | -c2/2 lo | zeros],
// cbT_bf[d][v] transposed bf16.
__global__ __launch_bounds__(256) void vq_prep_kernel(
    const float* __restrict__ cb,
    unsigned short* __restrict__ cb_ext,  // [V][KE]
    unsigned short* __restrict__ cbT_bf)  // [D][V]
{
    int v = blockIdx.x;
    int t = threadIdx.x;
    float val = cb[(size_t)v * DD + t];
    unsigned short h = f2bf(val);
    cb_ext[(size_t)v * KE + t] = h;
    cbT_bf[(size_t)t * VV + v] = h;
    float p = val * val;
#pragma unroll
    for (int d = 1; d < 64; d <<= 1) p += __shfl_xor(p, d);
    __shared__ float ps[4];
    if ((t & 63) == 0) ps[t >> 6] = p;
    __syncthreads();
    if (t < 32) {
        float c2 = ps[0] + ps[1] + ps[2] + ps[3];
        float m = -0.5f * c2;
        unsigned short hi = f2bf(m);
        float hif = __uint_as_float((unsigned int)hi << 16);
        unsigned short lo = f2bf(m - hif);
        unsigned short o = (t == 0) ? hi : ((t == 1) ? lo : (unsigned short)0);
        cb_ext[(size_t)v * KE + DD + t] = o;
    }
}

// accurate-enough -log(u): log1p poly near 1 (relative accuracy where it matters),
// hardware log elsewhere.
__device__ __forceinline__ float neg_log_u(float u) {
    float t = u - 1.0f;  // exact for u in [0.5, 1]
    float p = t * (1.0f + t * (-0.5f + t * (0.33333333f + t * (-0.25f + t * 0.2f))));
    float lg = (u >= 0.984375f) ? p : __logf(u);
    return -lg;
}

// Main fused kernel: one block = BN(16) rows, 4 waves.
// Swapped GEMM1 -> lane owns (x-row = lane&15, v = vb+16nt+4*lrow+r):
// gumbel loads and out_p stores are direct per-lane float4; softmax lane-local.
__global__ __launch_bounds__(256, 3) void vq_main_kernel(
    const float* __restrict__ x,          // [N][D]
    const float* __restrict__ gum,        // [N][V]
    const unsigned short* __restrict__ cb_ext,  // [V][KE]
    const unsigned short* __restrict__ cbT_bf,  // [D][V]
    float* __restrict__ out_q,            // [N][D]
    float* __restrict__ out_p)            // [N][V]
{
    __shared__ __align__(16) unsigned short ubuf[BN * VV];  // 32 KB bf16 prob tile
    __shared__ float sredA[4][BN];
    __shared__ float sredB[4][BN];

    const int tid  = threadIdx.x;
    const int wave = tid >> 6;
    const int lane = tid & 63;
    const int lrow = lane >> 4;   // 0..3
    const int lcol = lane & 15;   // 0..15
    const int row0 = blockIdx.x * BN;
    const int vb   = wave * 256;  // GEMM1: this wave's V-chunk base
    const int dbw  = wave * 64;   // GEMM2: this wave's D-chunk base

    // ---- Phase 0: x -> B-fragments (afr) in registers + x2 via shuffles ----
    // B[n = lcol (x-row)][k = 32kt + 8lrow + j]
    bf16x8 afr[9];
    float x2 = 0.f;
    {
        const float* xrow = x + (size_t)(row0 + lcol) * DD + lrow * 8;
        float4 xa[8], xb[8];
#pragma unroll
        for (int kt = 0; kt < 8; ++kt) {
            xa[kt] = *reinterpret_cast<const float4*>(xrow + kt * 32);
            xb[kt] = *reinterpret_cast<const float4*>(xrow + kt * 32 + 4);
        }
#pragma unroll
        for (int kt = 0; kt < 8; ++kt) {
            float v8[8] = {xa[kt].x, xa[kt].y, xa[kt].z, xa[kt].w,
                           xb[kt].x, xb[kt].y, xb[kt].z, xb[kt].w};
            uint32x4 w;
#pragma unroll
            for (int j = 0; j < 4; ++j) {
                x2 += v8[2 * j] * v8[2 * j] + v8[2 * j + 1] * v8[2 * j + 1];
                w[j] = (unsigned int)f2bf(v8[2 * j]) |
                       ((unsigned int)f2bf(v8[2 * j + 1]) << 16);
            }
            afr[kt] = __builtin_bit_cast(bf16x8, w);
        }
        x2 += __shfl_xor(x2, 16);
        x2 += __shfl_xor(x2, 32);   // x2 of row lcol, replicated — right lane already
        // ones-fragment for the c2 columns: k=256,257 carry 1.0 (lrow==0, j=0,1)
        uint32x4 w = {0u, 0u, 0u, 0u};
        if (lrow == 0) w[0] = 0x3F803F80u;  // two bf16 1.0
        afr[8] = __builtin_bit_cast(bf16x8, w);
    }

    // ---- GEMM1 (swapped): acc[nt] lane view: row=lcol, v=vb+16nt+4lrow+r ----
    // acc = x.cb - c2/2  (c2 folded via extended K)
    f32x4 acc[16];
#pragma unroll
    for (int nt = 0; nt < 16; ++nt) acc[nt] = (f32x4){0.f, 0.f, 0.f, 0.f};

#pragma unroll
    for (int nt = 0; nt < 16; ++nt) {
        const unsigned short* ap =
            cb_ext + (size_t)(vb + nt * 16 + lcol) * KE + lrow * 8;
#pragma unroll
        for (int kt = 0; kt < 9; ++kt) {
            bf16x8 cfr = __builtin_bit_cast(bf16x8,
                *reinterpret_cast<const uint32x4*>(ap + kt * 32));
            acc[nt] = __builtin_amdgcn_mfma_f32_16x16x32_bf16(cfr, afr[kt], acc[nt], 0, 0, 0);
        }
    }

    // ---- Gumbel: direct per-lane float4 loads (v-contiguous), 16-deep ----
    const float* grow = gum + (size_t)(row0 + lcol) * VV + vb + lrow * 4;
    float4 gu[16];
#pragma unroll
    for (int nt = 0; nt < 16; ++nt)
        gu[nt] = *reinterpret_cast<const float4*>(grow + nt * 16);

    // ---- logits + one-pass softmax (all values of a row are lane-local) ----
    float mp = -1e30f;
#pragma unroll
    for (int nt = 0; nt < 16; ++nt) {
        float uu[4] = {gu[nt].x, gu[nt].y, gu[nt].z, gu[nt].w};
#pragma unroll
        for (int r = 0; r < 4; ++r) {
            float u = fminf(fmaxf(uu[r], 1e-10f), 1.0f - 1e-10f);
            float w = neg_log_u(u);       // -log(u) > 0
            float g = -__logf(w);         // gumbel
            float d2 = fmaxf(x2 - 2.0f * acc[nt][r], 1e-12f);
            float lg = (g - sqrtf(d2)) * 0.5f;   // TEMP = 2
            acc[nt][r] = lg;
            mp = fmaxf(mp, lg);
        }
    }
    mp = fmaxf(mp, __shfl_xor(mp, 16));
    mp = fmaxf(mp, __shfl_xor(mp, 32));   // wave-local row max (over this v-chunk)

    float ss = 0.f;
#pragma unroll
    for (int nt = 0; nt < 16; ++nt) {
#pragma unroll
        for (int r = 0; r < 4; ++r) {
            float e = __expf(acc[nt][r] - mp);
            acc[nt][r] = e;
            ss += e;
        }
    }
    ss += __shfl_xor(ss, 16);
    ss += __shfl_xor(ss, 32);

    if (lane < 16) { sredA[wave][lcol] = mp; sredB[wave][lcol] = ss; }
    __syncthreads();

    // combine across waves: global max m, Z; f = exp(mp - m) / Z
    float m0 = sredA[0][lcol], m1 = sredA[1][lcol];
    float m2 = sredA[2][lcol], m3 = sredA[3][lcol];
    float m = fmaxf(fmaxf(m0, m1), fmaxf(m2, m3));
    float Z = sredB[0][lcol] * __expf(m0 - m) + sredB[1][lcol] * __expf(m1 - m) +
              sredB[2][lcol] * __expf(m2 - m) + sredB[3][lcol] * __expf(m3 - m);
    const float f = __expf(mp - m) / Z;

    // ---- P: normalize in regs; bf16 -> LDS (swizzled). Global stores deferred. ----
#pragma unroll
    for (int nt = 0; nt < 16; ++nt) {
        float p0 = acc[nt][0] * f, p1 = acc[nt][1] * f;
        float p2 = acc[nt][2] * f, p3 = acc[nt][3] * f;
        acc[nt] = (f32x4){p0, p1, p2, p3};
        uint2 pk;
        pk.x = (unsigned int)f2bf(p0) | ((unsigned int)f2bf(p1) << 16);
        pk.y = (unsigned int)f2bf(p2) | ((unsigned int)f2bf(p3) << 16);
        *reinterpret_cast<uint2*>(&ubuf[SWZ(lcol, vb + nt * 16 + lrow * 4)]) = pk;
    }
    __syncthreads();

    // ---- GEMM2: quantized[16][dbw..dbw+63] = prob[16][1024] @ cb[1024][256] ----
    f32x4 q[4];
#pragma unroll
    for (int nt = 0; nt < 4; ++nt) q[nt] = (f32x4){0.f, 0.f, 0.f, 0.f};

#pragma unroll
    for (int kt = 0; kt < 32; ++kt) {
        bf16x8 pfr = __builtin_bit_cast(bf16x8,
            *reinterpret_cast<const uint32x4*>(&ubuf[SWZ(lcol, kt * 32 + lrow * 8)]));
#pragma unroll
        for (int nt = 0; nt < 4; ++nt) {
            const unsigned short* bp =
                cbT_bf + (size_t)(dbw + nt * 16 + lcol) * VV + kt * 32 + lrow * 8;
            bf16x8 bfr = __builtin_bit_cast(bf16x8,
                *reinterpret_cast<const uint32x4*>(bp));
            q[nt] = __builtin_amdgcn_mfma_f32_16x16x32_bf16(pfr, bfr, q[nt], 0, 0, 0);
        }
    }

    // ---- out_p: direct per-lane float4 stores (exact f32, v-contiguous) ----
    {
        float* oprow = out_p + (size_t)(row0 + lcol) * VV + vb + lrow * 4;
#pragma unroll
        for (int nt = 0; nt < 16; ++nt)
            *reinterpret_cast<float4*>(oprow + nt * 16) =
                (float4){acc[nt][0], acc[nt][1], acc[nt][2], acc[nt][3]};
    }

    // ---- out_q: direct store (waves own disjoint D-chunks) ----
#pragma unroll
    for (int nt = 0; nt < 4; ++nt) {
        const int d = dbw + nt * 16 + lcol;
#pragma unroll
        for (int r = 0; r < 4; ++r) {
            const int row = lrow * 4 + r;
            out_q[(size_t)(row0 + row) * DD + d] = q[nt][r];
        }
    }
}

extern "C" void kernel_launch(void* const* d_in, const int* in_sizes, int n_in,
                              void* d_out, int out_size, void* d_ws, size_t ws_size,
                              hipStream_t stream) {
    (void)in_sizes; (void)n_in; (void)out_size; (void)ws_size;
    const float* x   = (const float*)d_in[0];   // [16,4096,256]
    const float* cb  = (const float*)d_in[1];   // [1024,256]
    const float* gum = (const float*)d_in[2];   // [65536,1024]

    const int N = 16 * 4096;
    float* out_q = (float*)d_out;                       // [N][256]
    float* out_p = out_q + (size_t)N * DD;              // [N][1024]

    unsigned short* cb_ext = (unsigned short*)d_ws;     // 576 KB
    unsigned short* cbT_bf = cb_ext + (size_t)VV * KE;  // 512 KB
    vq_prep_kernel<<<VV, 256, 0, stream>>>(cb, cb_ext, cbT_bf);
    vq_main_kernel<<<N / BN, 256, 0, stream>>>(x, gum, cb_ext, cbT_bf, out_q, out_p);
}

// Round 6
// 451.648 us; speedup vs baseline: 1.6530x; 1.1375x over previous
//
#include <hip/hip_runtime.h>

typedef __bf16 bf16x8 __attribute__((ext_vector_type(8)));
typedef float f32x4 __attribute__((ext_vector_type(4)));
typedef unsigned int uint32x4 __attribute__((ext_vector_type(4)));

#define DD 256
#define VV 1024
#define BN 16
#define KC1 36   // extended-K chunks of 8 (288/8): 32 data + c2 + zeros

// XOR swizzle on ushort index: flips element-index bits 3..5 by row ->
// bank-spread for stride-2KB column reads while keeping 8B/16B chunks intact.
#define SWZ(row, col) ((((row) * VV) + (col)) ^ (((row) & 7) << 3))

__device__ __forceinline__ unsigned short f2bf(float f) {
    unsigned int b = __float_as_uint(f);
    b += 0x7FFFu + ((b >> 16) & 1u);
    return (unsigned short)(b >> 16);
}

// Prep: fragment-major codebook layouts.
// cbA[vtile=v/16][kc=0..35][i=v%16][j=0..7]: kc<32 -> cb[v][kc*8+j] bf16;
//   kc=32,j=0 -> hi(-c2/2), kc=32,j=1 -> lo, else 0.
// cbB[dtile=d/16][kc=v/8][i=d%16][j=v%8] = cb[v][d] bf16.
__global__ __launch_bounds__(256) void vq_prep_kernel(
    const float* __restrict__ cb,
    unsigned short* __restrict__ cbA,   // [V/16][KC1][16][8]
    unsigned short* __restrict__ cbB)   // [D/16][128][16][8]
{
    int v = blockIdx.x;
    int t = threadIdx.x;
    float val = cb[(size_t)v * DD + t];
    unsigned short h = f2bf(val);
    const int vtile = v >> 4, vi = v & 15;
    cbA[(((size_t)vtile * KC1 + (t >> 3)) * 16 + vi) * 8 + (t & 7)] = h;
    cbB[(((size_t)(t >> 4) * 128 + (v >> 3)) * 16 + (t & 15)) * 8 + (v & 7)] = h;
    float p = val * val;
#pragma unroll
    for (int d = 1; d < 64; d <<= 1) p += __shfl_xor(p, d);
    __shared__ float ps[4];
    if ((t & 63) == 0) ps[t >> 6] = p;
    __syncthreads();
    if (t < 32) {
        float c2 = ps[0] + ps[1] + ps[2] + ps[3];
        float m = -0.5f * c2;
        unsigned short hi = f2bf(m);
        float hif = __uint_as_float((unsigned int)hi << 16);
        unsigned short lo = f2bf(m - hif);
        unsigned short o = (t == 0) ? hi : ((t == 1) ? lo : (unsigned short)0);
        cbA[(((size_t)vtile * KC1 + 32 + (t >> 3)) * 16 + vi) * 8 + (t & 7)] = o;
    }
}

// accurate-enough -log(u): log1p poly near 1 (relative accuracy where it matters),
// hardware log elsewhere.
__device__ __forceinline__ float neg_log_u(float u) {
    float t = u - 1.0f;  // exact for u in [0.5, 1]
    float p = t * (1.0f + t * (-0.5f + t * (0.33333333f + t * (-0.25f + t * 0.2f))));
    float lg = (u >= 0.984375f) ? p : __logf(u);
    return -lg;
}

// Main fused kernel: one block = BN(16) rows, 4 waves.
// Swapped GEMM1 -> lane owns (x-row = lane&15, v = vb+16nt+4*lrow+r).
__global__ __launch_bounds__(256, 3) void vq_main_kernel(
    const float* __restrict__ x,          // [N][D]
    const float* __restrict__ gum,        // [N][V]
    const unsigned short* __restrict__ cbA,
    const unsigned short* __restrict__ cbB,
    float* __restrict__ out_q,            // [N][D]
    float* __restrict__ out_p)            // [N][V]
{
    __shared__ __align__(16) unsigned short ubuf[BN * VV];  // 32 KB bf16 prob tile
    __shared__ float sredA[4][BN];
    __shared__ float sredB[4][BN];

    const int tid  = threadIdx.x;
    const int wave = tid >> 6;
    const int lane = tid & 63;
    const int lrow = lane >> 4;   // 0..3
    const int lcol = lane & 15;   // 0..15
    const int row0 = blockIdx.x * BN;
    const int vb   = wave * 256;  // GEMM1: this wave's V-chunk base
    const int dbw  = wave * 64;   // GEMM2: this wave's D-chunk base

    // ---- Phase 0: x -> B-fragments (afr) in registers + x2 via shuffles ----
    // B[n = lcol (x-row)][k = 32kt + 8lrow + j]
    bf16x8 afr[9];
    float x2 = 0.f;
    {
        const float* xrow = x + (size_t)(row0 + lcol) * DD + lrow * 8;
        float4 xa[8], xb[8];
#pragma unroll
        for (int kt = 0; kt < 8; ++kt) {
            xa[kt] = *reinterpret_cast<const float4*>(xrow + kt * 32);
            xb[kt] = *reinterpret_cast<const float4*>(xrow + kt * 32 + 4);
        }
#pragma unroll
        for (int kt = 0; kt < 8; ++kt) {
            float v8[8] = {xa[kt].x, xa[kt].y, xa[kt].z, xa[kt].w,
                           xb[kt].x, xb[kt].y, xb[kt].z, xb[kt].w};
            uint32x4 w;
#pragma unroll
            for (int j = 0; j < 4; ++j) {
                x2 += v8[2 * j] * v8[2 * j] + v8[2 * j + 1] * v8[2 * j + 1];
                w[j] = (unsigned int)f2bf(v8[2 * j]) |
                       ((unsigned int)f2bf(v8[2 * j + 1]) << 16);
            }
            afr[kt] = __builtin_bit_cast(bf16x8, w);
        }
        x2 += __shfl_xor(x2, 16);
        x2 += __shfl_xor(x2, 32);   // x2 of row lcol, replicated
        uint32x4 w = {0u, 0u, 0u, 0u};
        if (lrow == 0) w[0] = 0x3F803F80u;  // two bf16 1.0 at k=256,257
        afr[8] = __builtin_bit_cast(bf16x8, w);
    }

    // gumbel chunk 0 issued early (hidden under GEMM1)
    const float* grow = gum + (size_t)(row0 + lcol) * VV + vb + lrow * 4;
    float4 gcur[4], gnxt[4];
#pragma unroll
    for (int i = 0; i < 4; ++i)
        gcur[i] = *reinterpret_cast<const float4*>(grow + i * 16);

    // ---- GEMM1 (swapped): acc[nt]: v = vb+16nt+4lrow+r, x-row = lcol ----
    // fragment-major loads: uniform base per nt + lane offset + imm per kt
    f32x4 acc[16];
#pragma unroll
    for (int nt = 0; nt < 16; ++nt) acc[nt] = (f32x4){0.f, 0.f, 0.f, 0.f};

    const int laneoff = lrow * 128 + lcol * 8;   // (kc%4)*128 + i*8 elems
#pragma unroll
    for (int nt = 0; nt < 16; ++nt) {
        const unsigned short* ap =
            cbA + ((size_t)(vb >> 4) + nt) * (KC1 * 128) + laneoff;
#pragma unroll
        for (int kt = 0; kt < 9; ++kt) {
            bf16x8 cfr = __builtin_bit_cast(bf16x8,
                *reinterpret_cast<const uint32x4*>(ap + kt * 512));
            acc[nt] = __builtin_amdgcn_mfma_f32_16x16x32_bf16(cfr, afr[kt], acc[nt], 0, 0, 0);
        }
    }

    // ---- logits + one-pass softmax, gumbel pipelined 4-deep ----
    float mp = -1e30f;
#pragma unroll
    for (int c = 0; c < 4; ++c) {
        if (c < 3) {
#pragma unroll
            for (int i = 0; i < 4; ++i)
                gnxt[i] = *reinterpret_cast<const float4*>(grow + (c * 4 + 4 + i) * 16);
        }
#pragma unroll
        for (int i = 0; i < 4; ++i) {
            const int nt = c * 4 + i;
            float uu[4] = {gcur[i].x, gcur[i].y, gcur[i].z, gcur[i].w};
#pragma unroll
            for (int r = 0; r < 4; ++r) {
                float u = fminf(fmaxf(uu[r], 1e-10f), 1.0f - 1e-10f);
                float w = neg_log_u(u);       // -log(u) > 0
                float g = -__logf(w);         // gumbel
                float d2 = fmaxf(x2 - 2.0f * acc[nt][r], 1e-12f);
                float lg = (g - sqrtf(d2)) * 0.5f;   // TEMP = 2
                acc[nt][r] = lg;
                mp = fmaxf(mp, lg);
            }
        }
#pragma unroll
        for (int i = 0; i < 4; ++i) gcur[i] = gnxt[i];
    }
    mp = fmaxf(mp, __shfl_xor(mp, 16));
    mp = fmaxf(mp, __shfl_xor(mp, 32));   // wave-local row max

    float ss = 0.f;
#pragma unroll
    for (int nt = 0; nt < 16; ++nt) {
#pragma unroll
        for (int r = 0; r < 4; ++r) {
            float e = __expf(acc[nt][r] - mp);
            acc[nt][r] = e;
            ss += e;
        }
    }
    ss += __shfl_xor(ss, 16);
    ss += __shfl_xor(ss, 32);

    if (lane < 16) { sredA[wave][lcol] = mp; sredB[wave][lcol] = ss; }
    __syncthreads();

    // combine across waves: global max m, Z; f = exp(mp - m) / Z
    float m0 = sredA[0][lcol], m1 = sredA[1][lcol];
    float m2 = sredA[2][lcol], m3 = sredA[3][lcol];
    float m = fmaxf(fmaxf(m0, m1), fmaxf(m2, m3));
    float Z = sredB[0][lcol] * __expf(m0 - m) + sredB[1][lcol] * __expf(m1 - m) +
              sredB[2][lcol] * __expf(m2 - m) + sredB[3][lcol] * __expf(m3 - m);
    const float f = __expf(mp - m) / Z;

    // ---- P -> bf16 LDS (swizzled); acc dies here ----
#pragma unroll
    for (int nt = 0; nt < 16; ++nt) {
        uint2 pk;
        pk.x = (unsigned int)f2bf(acc[nt][0] * f) |
               ((unsigned int)f2bf(acc[nt][1] * f) << 16);
        pk.y = (unsigned int)f2bf(acc[nt][2] * f) |
               ((unsigned int)f2bf(acc[nt][3] * f) << 16);
        *reinterpret_cast<uint2*>(&ubuf[SWZ(lcol, vb + nt * 16 + lrow * 4)]) = pk;
    }
    __syncthreads();

    // ---- GEMM2: quantized[16][dbw..dbw+63] = prob[16][1024] @ cb[1024][256] ----
    f32x4 q[4];
#pragma unroll
    for (int nt = 0; nt < 4; ++nt) q[nt] = (f32x4){0.f, 0.f, 0.f, 0.f};

    const unsigned short* bb[4];
#pragma unroll
    for (int nt = 0; nt < 4; ++nt)
        bb[nt] = cbB + ((size_t)(dbw >> 4) + nt) * (128 * 128) + laneoff;

#pragma unroll
    for (int kt = 0; kt < 32; ++kt) {
        bf16x8 pfr = __builtin_bit_cast(bf16x8,
            *reinterpret_cast<const uint32x4*>(&ubuf[SWZ(lcol, kt * 32 + lrow * 8)]));
#pragma unroll
        for (int nt = 0; nt < 4; ++nt) {
            bf16x8 bfr = __builtin_bit_cast(bf16x8,
                *reinterpret_cast<const uint32x4*>(bb[nt] + kt * 512));
            q[nt] = __builtin_amdgcn_mfma_f32_16x16x32_bf16(pfr, bfr, q[nt], 0, 0, 0);
        }
    }

    // ---- out_p: reconstruct f32 from LDS bf16, coalesced float4 stores ----
    {
        const int prow = (wave << 2) | lrow;   // 0..15
        float* oprow = out_p + (size_t)(row0 + prow) * VV;
#pragma unroll
        for (int c = 0; c < 8; ++c) {
            const int col = c * 128 + lcol * 8;
            uint32x4 pw = *reinterpret_cast<const uint32x4*>(&ubuf[SWZ(prow, col)]);
            float o[8];
#pragma unroll
            for (int j = 0; j < 4; ++j) {
                o[2 * j]     = __uint_as_float(pw[j] << 16);
                o[2 * j + 1] = __uint_as_float(pw[j] & 0xFFFF0000u);
            }
            *reinterpret_cast<float4*>(oprow + col)     = (float4){o[0], o[1], o[2], o[3]};
            *reinterpret_cast<float4*>(oprow + col + 4) = (float4){o[4], o[5], o[6], o[7]};
        }
    }

    // ---- out_q: 4 row bases + imm offsets (waves own disjoint D-chunks) ----
    {
        float* qrow0 = out_q + (size_t)(row0 + lrow * 4) * DD + dbw + lcol;
#pragma unroll
        for (int r = 0; r < 4; ++r) {
            float* qr = qrow0 + r * DD;
#pragma unroll
            for (int nt = 0; nt < 4; ++nt) qr[nt * 16] = q[nt][r];
        }
    }
}

extern "C" void kernel_launch(void* const* d_in, const int* in_sizes, int n_in,
                              void* d_out, int out_size, void* d_ws, size_t ws_size,
                              hipStream_t stream) {
    (void)in_sizes; (void)n_in; (void)out_size; (void)ws_size;
    const float* x   = (const float*)d_in[0];   // [16,4096,256]
    const float* cb  = (const float*)d_in[1];   // [1024,256]
    const float* gum = (const float*)d_in[2];   // [65536,1024]

    const int N = 16 * 4096;
    float* out_q = (float*)d_out;                       // [N][256]
    float* out_p = out_q + (size_t)N * DD;              // [N][1024]

    unsigned short* cbA = (unsigned short*)d_ws;        // 576 KB fragment-major
    unsigned short* cbB = cbA + (size_t)64 * KC1 * 128; // 512 KB fragment-major
    vq_prep_kernel<<<VV, 256, 0, stream>>>(cb, cbA, cbB);
    vq_main_kernel<<<N / BN, 256, 0, stream>>>(x, gum, cbA, cbB, out_q, out_p);
}